// Round 21
// baseline (957.397 us; speedup 1.0000x reference)
//
#include <hip/hip_runtime.h>
#include <math.h>

typedef unsigned short u16;
typedef unsigned int u32;
typedef __attribute__((ext_vector_type(8))) short short8;
typedef __attribute__((ext_vector_type(4))) float f32x4;

#define IMG 56
#define HW_ 3136
#define NTOK 50176
#define C_DIM 192
#define CONV_OUT_SZ 4816896  /* 16*96*3136 floats */

#define SZ_QKV (4*576*192)
#define SZ_FC1 (4*768*192)
#define SZ_FC2 (4*192*768)
#define SZ_PW  (4*192*192)
#define SZ_PROJ (192*192)
#define SZ_C1R (192*1728)
#define SZ_C2R (128*1728)

__device__ inline float bf2f(u16 v) {
  u32 u = ((u32)v) << 16; float f; __builtin_memcpy(&f, &u, 4); return f;
}
__device__ inline u16 f2bf(float f) {
  u32 u; __builtin_memcpy(&u, &f, 4);
  u += 0x7FFF + ((u >> 16) & 1);
  return (u16)(u >> 16);
}
__device__ inline void glds16(const u16* g, u16* l) {
  __builtin_amdgcn_global_load_lds((const __attribute__((address_space(1))) u32*)g,
                                   (__attribute__((address_space(3))) u32*)l, 16, 0, 0);
}
__device__ inline u32 pk_bf16(float a, float b) {
  u32 r;
  asm("v_cvt_pk_bf16_f32 %0, %1, %2" : "=v"(r) : "v"(a), "v"(b));
  return r;
}

// XCD-aware decode for the conv GEMMs (r20-proven)
__device__ inline void xcd_decode(int f, int NB, int& mb, int& nb) {
  const int ml = f & 7;
  const int rest = f >> 3;
  nb = rest % NB;
  mb = (rest / NB) * 8 + ml;
}

// ---------------------------------------------------------------------------
// MFMA bf16 GEMM, 128x64 tile (conv path): single-buffered 24KB LDS, 4 waves.
// EPI 3: BN+relu->bf16 NHWC.  EPI 4: BN+relu->f32 NCHW (guard c<N).
// AMODE 1: implicit im2col gather with K-invariant row geometry hoisted.
// ---------------------------------------------------------------------------
template<int AMODE, int EPI>
__global__ __launch_bounds__(256) void gmm(
    const u16* __restrict__ A, const u16* __restrict__ W,
    const float* __restrict__ bias, void* __restrict__ Cout,
    int M, int N, int K, int NB,
    const float* __restrict__ bg, const float* __restrict__ bb,
    const float* __restrict__ bm, const float* __restrict__ bv, int shiftp)
{
  __shared__ u16 As[128 * 64];
  __shared__ u16 Bs[64 * 64];
  const int tid = threadIdx.x;
  int mb, nb;
  xcd_decode(blockIdx.x, NB, mb, nb);
  const int m0 = mb * 128, n0 = nb * 64;
  const int lane = tid & 63, wid = tid >> 6;
  const int wm = (wid >> 1) * 64, wn = (wid & 1) * 32;
  const int fr = lane & 15, fg = lane >> 4;
  f32x4 acc[4][2] = {};

  const u16* rowp0; const u16* rowp1; const u16* rowp2; const u16* rowp3;
  int ry0, ry1, ry2, ry3, rx0, rx1, rx2, rx3;
  if (AMODE == 1) {
    #pragma unroll
    for (int it = 0; it < 4; ++it) {
      const int g = it * 256 + tid;
      const int row = g >> 3;
      const int m = m0 + row;
      const int b = m / HW_, pp = m - b * HW_;
      const int y = pp / IMG, x = pp - (pp / IMG) * IMG;
      const u16* rp = A + ((size_t)(b * HW_ + y * IMG + x)) * C_DIM;
      if (it == 0) { rowp0 = rp; ry0 = y; rx0 = x; }
      else if (it == 1) { rowp1 = rp; ry1 = y; rx1 = x; }
      else if (it == 2) { rowp2 = rp; ry2 = y; rx2 = x; }
      else { rowp3 = rp; ry3 = y; rx3 = x; }
    }
  }

  for (int kc = 0; kc < K; kc += 64) {
    #pragma unroll
    for (int it = 0; it < 2; ++it) {
      const int g = it * 256 + tid;
      const int row = g >> 3, cb = (g & 7) << 4;
      const int sc = cb ^ ((row & 7) << 4);
      glds16(W + (size_t)(n0 + row) * K + kc + (sc >> 1), Bs + g * 8);
    }
    if (AMODE == 0) {
      #pragma unroll
      for (int it = 0; it < 4; ++it) {
        const int g = it * 256 + tid;
        const int row = g >> 3, cb = (g & 7) << 4;
        const int sc = cb ^ ((row & 7) << 4);
        glds16(A + (size_t)(m0 + row) * K + kc + (sc >> 1), As + g * 8);
      }
    } else {
      #pragma unroll
      for (int it = 0; it < 4; ++it) {
        const int g = it * 256 + tid;
        const int row = g >> 3, cb = (g & 7) << 4;
        const int kg = kc + (cb >> 1);
        const int s = kg / C_DIM, ic = kg - s * C_DIM;
        const int dy = s / 3 - 1, dx = s % 3 - 1;
        const u16* rp = (it == 0) ? rowp0 : (it == 1) ? rowp1 : (it == 2) ? rowp2 : rowp3;
        const int y = (it == 0) ? ry0 : (it == 1) ? ry1 : (it == 2) ? ry2 : ry3;
        const int x = (it == 0) ? rx0 : (it == 1) ? rx1 : (it == 2) ? rx2 : rx3;
        const int yy = y + dy, xx = x + dx;
        short8 v = {0, 0, 0, 0, 0, 0, 0, 0};
        if ((unsigned)yy < IMG && (unsigned)xx < IMG)
          v = *(const short8*)(rp + (dy * IMG + dx) * C_DIM + ic);
        *(short8*)(As + row * 64 + ((cb ^ ((row & 7) << 4)) >> 1)) = v;
      }
    }
    __syncthreads();
    #pragma unroll
    for (int ks = 0; ks < 2; ++ks) {
      const int kb = ks * 64 + fg * 16;
      short8 af[4], bfv[2];
      #pragma unroll
      for (int i = 0; i < 4; ++i) {
        const int row = wm + i * 16 + fr;
        af[i] = *(const short8*)(As + ((row * 128 + (kb ^ ((row & 7) << 4))) >> 1));
      }
      #pragma unroll
      for (int j = 0; j < 2; ++j) {
        const int row = wn + j * 16 + fr;
        bfv[j] = *(const short8*)(Bs + ((row * 128 + (kb ^ ((row & 7) << 4))) >> 1));
      }
      #pragma unroll
      for (int i = 0; i < 4; ++i)
        #pragma unroll
        for (int j = 0; j < 2; ++j)
          acc[i][j] = __builtin_amdgcn_mfma_f32_16x16x32_bf16(af[i], bfv[j], acc[i][j], 0, 0, 0);
    }
    __syncthreads();
  }

  const int c0 = n0 + wn + fr;
  const int c1i = (EPI == 4) ? min(c0 + 16, N - 1) : (c0 + 16);
  const float bias0 = bias[c0], bias1 = bias[c1i];
  const float s0 = bg[c0] * rsqrtf(bv[c0] + 1e-5f);
  const float h0 = bb[c0] - bm[c0] * s0;
  const float s1 = bg[c1i] * rsqrtf(bv[c1i] + 1e-5f);
  const float h1 = bb[c1i] - bm[c1i] * s1;

  #pragma unroll
  for (int i = 0; i < 4; ++i) {
    #pragma unroll
    for (int r = 0; r < 4; ++r) {
      const int m = m0 + wm + i * 16 + fg * 4 + r;
      #pragma unroll
      for (int j = 0; j < 2; ++j) {
        const int c = c0 + j * 16;
        float v = acc[i][j][r] + (j ? bias1 : bias0);
        v = v * (j ? s1 : s0) + (j ? h1 : h0);
        v = fmaxf(v, 0.f);
        if (EPI == 3) {
          ((u16*)Cout)[(size_t)m * N + c] = f2bf(v);
        } else {
          if (c < N) {
            const int b = m / HW_, pp = m - b * HW_;
            ((float*)Cout)[((size_t)b * N + c) * HW_ + pp] = v;
          }
        }
      }
    }
  }
}

// ---------------------------------------------------------------------------
// N-persistent BM=64 GEMM: grid = M/64 blocks; each block loops over the full
// N in 64-wide sub-tiles, so its A-panel is read from L3 once and from the
// block's own L2 thereafter.  4 waves as 2x2 (each 32x32, acc[2][2]), 16KB LDS.
// EPI: 0 store bf16, 1 gelu->bf16, 2 +=bf16 vector RMW,
//      6 win-reverse + roll(+shiftp) +=bf16 NHWC act (vector RMW per row).
// ---------------------------------------------------------------------------
template<int EPI>
__global__ __launch_bounds__(256) void gmm64(
    const u16* __restrict__ A, const u16* __restrict__ W,
    const float* __restrict__ bias, void* __restrict__ Cout,
    int M, int N, int K, int NLOOP, int shiftp)
{
  __shared__ u16 As[64 * 64];
  __shared__ u16 Bs[64 * 64];
  const int tid = threadIdx.x;
  const int m0 = blockIdx.x * 64;
  const int lane = tid & 63, wid = tid >> 6;
  const int wm = (wid >> 1) * 32, wn = (wid & 1) * 32;
  const int fr = lane & 15, fg = lane >> 4;

  for (int nb2 = 0; nb2 < NLOOP; ++nb2) {
    const int n0 = nb2 * 64;
    f32x4 acc[2][2] = {};
    for (int kc = 0; kc < K; kc += 64) {
      #pragma unroll
      for (int it = 0; it < 2; ++it) {
        const int g = it * 256 + tid;
        const int row = g >> 3, cb = (g & 7) << 4;
        const int sc = cb ^ ((row & 7) << 4);
        glds16(W + (size_t)(n0 + row) * K + kc + (sc >> 1), Bs + g * 8);
        glds16(A + (size_t)(m0 + row) * K + kc + (sc >> 1), As + g * 8);
      }
      __syncthreads();
      #pragma unroll
      for (int ks = 0; ks < 2; ++ks) {
        const int kb = ks * 64 + fg * 16;
        short8 af[2], bfv[2];
        #pragma unroll
        for (int i = 0; i < 2; ++i) {
          const int row = wm + i * 16 + fr;
          af[i] = *(const short8*)(As + ((row * 128 + (kb ^ ((row & 7) << 4))) >> 1));
        }
        #pragma unroll
        for (int j = 0; j < 2; ++j) {
          const int row = wn + j * 16 + fr;
          bfv[j] = *(const short8*)(Bs + ((row * 128 + (kb ^ ((row & 7) << 4))) >> 1));
        }
        #pragma unroll
        for (int i = 0; i < 2; ++i)
          #pragma unroll
          for (int j = 0; j < 2; ++j)
            acc[i][j] = __builtin_amdgcn_mfma_f32_16x16x32_bf16(af[i], bfv[j], acc[i][j], 0, 0, 0);
      }
      __syncthreads();
    }

    // ---- epilogue for this n-subtile (transposed swizzled-LDS -> 16B access)
    const int c0 = n0 + wn + fr;
    const float bias0 = bias[c0], bias1 = bias[c0 + 16];
    #pragma unroll
    for (int i = 0; i < 2; ++i) {
      #pragma unroll
      for (int r = 0; r < 4; ++r) {
        const int ml = wm + i * 16 + fg * 4 + r;
        #pragma unroll
        for (int j = 0; j < 2; ++j) {
          float v = acc[i][j][r] + (j ? bias1 : bias0);
          if (EPI == 1) v = 0.5f * v * (1.f + erff(v * 0.70710678118f));
          const int cl = wn + j * 16 + fr;
          As[ml * 64 + ((cl & 7) | ((((cl >> 3) ^ ml) & 7) << 3))] = f2bf(v);
        }
      }
    }
    __syncthreads();
    #pragma unroll
    for (int p = 0; p < 2; ++p) {
      const int id = p * 256 + tid;
      const int ml = id >> 3, grp = id & 7;
      const int pg = (grp ^ ml) & 7;
      const short8 vv = *(const short8*)(As + ml * 64 + pg * 8);
      if (EPI == 0 || EPI == 1) {
        *(short8*)((u16*)Cout + (size_t)(m0 + ml) * N + n0 + grp * 8) = vv;
      } else {
        size_t dstoff;
        if (EPI == 2) {
          dstoff = (size_t)(m0 + ml) * N + n0 + grp * 8;
        } else {  // EPI 6
          const int m = m0 + ml;
          const int wno = m / 49, within = m - wno * 49;
          const int b2 = wno >> 6, wb3 = wno & 63;
          const int wr = within / 7, wc = within - wr * 7;
          int y2 = (wb3 >> 3) * 7 + wr + shiftp; if (y2 >= IMG) y2 -= IMG;
          int x2 = (wb3 & 7) * 7 + wc + shiftp; if (x2 >= IMG) x2 -= IMG;
          dstoff = ((size_t)(b2 * HW_ + y2 * IMG + x2)) * C_DIM + n0 + grp * 8;
        }
        u16* p8 = (u16*)Cout + dstoff;
        const short8 old = *(const short8*)p8;
        const u16* av_ = (const u16*)&vv;
        const u16* ov_ = (const u16*)&old;
        u32 res[4];
        #pragma unroll
        for (int e = 0; e < 4; ++e)
          res[e] = pk_bf16(bf2f(ov_[2 * e]) + bf2f(av_[2 * e]),
                           bf2f(ov_[2 * e + 1]) + bf2f(av_[2 * e + 1]));
        *(short8*)p8 = *(const short8*)res;
      }
    }
    __syncthreads();  // As reads done before next n-iter staging
  }
}

// ---------------------------------------------------------------------------
// LayerNorm over C=192, bf16 in / bf16 out, wave-per-token (4 tokens/block).
// ---------------------------------------------------------------------------
__global__ __launch_bounds__(256) void ln_k(
    const u16* __restrict__ in, u16* __restrict__ outp,
    const float* __restrict__ g, const float* __restrict__ bta,
    const float* __restrict__ pos, int winpart, int shift)
{
  const int t = blockIdx.x * 4 + (threadIdx.x >> 6);
  const int lane = threadIdx.x & 63;
  const uint2* row = (const uint2*)(in + (size_t)t * C_DIM);
  uint2 w = make_uint2(0, 0);
  if (lane < 48) w = row[lane];
  const float v0 = bf2f((u16)w.x), v1 = bf2f(w.x >> 16);
  const float v2 = bf2f((u16)w.y), v3 = bf2f(w.y >> 16);
  float s = v0 + v1 + v2 + v3;
  float ss = v0 * v0 + v1 * v1 + v2 * v2 + v3 * v3;
  #pragma unroll
  for (int off = 32; off > 0; off >>= 1) {
    s += __shfl_xor(s, off);
    ss += __shfl_xor(ss, off);
  }
  const float mean = s * (1.f / 192.f);
  const float inv = rsqrtf(ss * (1.f / 192.f) - mean * mean + 1e-5f);
  const int b = t / HW_, pp = t - b * HW_;
  size_t obase;
  if (winpart) {
    const int y = pp / IMG, x = pp - (pp / IMG) * IMG;
    int yr = y - shift; if (yr < 0) yr += IMG;
    int xs = x - shift; if (xs < 0) xs += IMG;
    const int win = b * 64 + (yr / 7) * 8 + (xs / 7);
    const int within = (yr % 7) * 7 + (xs % 7);
    obase = ((size_t)win * 49 + within) * C_DIM;
  } else {
    obase = (size_t)t * C_DIM;
  }
  if (lane < 48) {
    const float4 gg = *(const float4*)(g + lane * 4);
    const float4 bb = *(const float4*)(bta + lane * 4);
    float p0 = 0.f, p1 = 0.f, p2 = 0.f, p3 = 0.f;
    if (pos) {
      const float4 pv = *(const float4*)(pos + (size_t)pp * C_DIM + lane * 4);
      p0 = pv.x; p1 = pv.y; p2 = pv.z; p3 = pv.w;
    }
    const float r0 = (v0 - mean) * inv * gg.x + bb.x + p0;
    const float r1 = (v1 - mean) * inv * gg.y + bb.y + p1;
    const float r2 = (v2 - mean) * inv * gg.z + bb.z + p2;
    const float r3 = (v3 - mean) * inv * gg.w + bb.w + p3;
    ((uint2*)(outp + obase))[lane] = make_uint2(pk_bf16(r0, r1), pk_bf16(r2, r3));
  }
}

// ---------------------------------------------------------------------------
// MFMA window attention, swapped-QK^T + sigma-order PV (P stays in registers).
// ---------------------------------------------------------------------------
template<int SHIFT>
__global__ __launch_bounds__(256) void attn_m(
    const u16* __restrict__ qkv, u16* __restrict__ outp,
    const float* __restrict__ rel)
{
  __shared__ u16 VT[128 * 64];
  __shared__ float relS[4 * 176 + 16];
  const int tid = threadIdx.x;
  const int wid = tid >> 6, lane = tid & 63;
  const int fr = lane & 15, fg = lane >> 4;
  const int win = blockIdx.x >> 1;
  const int hb = blockIdx.x & 1;
  const int h = hb * 4 + wid;
  const u16* wbase = qkv + (size_t)win * 49 * 576;

  {
    u32* vz = (u32*)VT;
    #pragma unroll
    for (int it = 0; it < 16; ++it) vz[it * 256 + tid] = 0;
  }
  for (int id = tid; id < 169 * 4; id += 256) {
    const int hl = id & 3, ridx = id >> 2;
    relS[hl * 176 + ridx] = rel[ridx * 8 + hb * 4 + hl];
  }
  __syncthreads();
  for (int id = tid; id < 49 * 24; id += 256) {
    const int j = id / 24, dq = id - (id / 24) * 24;
    const int dd = dq * 4;
    const uint2 v = *(const uint2*)(wbase + j * 576 + 384 + hb * 96 + dd);
    const u16* pv = (const u16*)&v;
    const int wpr = dd / 24, dl = dd - wpr * 24;
    #pragma unroll
    for (int e = 0; e < 4; ++e) {
      const int row = wpr * 32 + dl + e;
      VT[(row * 128 + ((j * 2) ^ (((row >> 2) & 7) << 4))) >> 1] = pv[e];
    }
  }
  __syncthreads();

  short8 qf[4], kf[4];
  #pragma unroll
  for (int t = 0; t < 4; ++t) {
    const int row = t * 16 + fr;
    if (fg < 3) {
      qf[t] = *(const short8*)(wbase + row * 576 + h * 24 + fg * 8);
      kf[t] = *(const short8*)(wbase + row * 576 + 192 + h * 24 + fg * 8);
    } else {
      qf[t] = (short8){0, 0, 0, 0, 0, 0, 0, 0};
      kf[t] = (short8){0, 0, 0, 0, 0, 0, 0, 0};
    }
  }

  short8 av[2][2];
  #pragma unroll
  for (int db = 0; db < 2; ++db) {
    const int row = wid * 32 + db * 16 + fr;
    const int swz = ((row >> 2) & 7) << 4;
    #pragma unroll
    for (int ks = 0; ks < 2; ++ks) {
      const uint2 lo = *(const uint2*)((const char*)VT + row * 128 + (((2 * ks) * 32 + fg * 8) ^ swz));
      const uint2 hi = *(const uint2*)((const char*)VT + row * 128 + (((2 * ks + 1) * 32 + fg * 8) ^ swz));
      u32 w[4] = {lo.x, lo.y, hi.x, hi.y};
      av[db][ks] = *(short8*)w;
    }
  }

  const int wb2 = win & 63;
  const int hblk = wb2 >> 3, wblk = wb2 & 7;

  u32 joffPk[4];
  u32 jregPk[2] = {0, 0};
  #pragma unroll
  for (int nj = 0; nj < 4; ++nj) {
    u32 w = 0;
    #pragma unroll
    for (int r = 0; r < 4; ++r) {
      const int j = nj * 16 + fg * 4 + r;
      const int r2 = j / 7, c2 = j - r2 * 7;
      w |= (u32)(r2 * 13 + c2) << (r * 8);
      if (SHIFT) {
        const int hj = hblk * 7 + r2, wj = wblk * 7 + c2;
        const int rj = (hj < 49 ? 0 : (hj < 53 ? 1 : 2)) * 3 + (wj < 49 ? 0 : (wj < 53 ? 1 : 2));
        jregPk[nj >> 1] |= (u32)rj << (((nj & 1) * 4 + r) * 4);
      }
    }
    joffPk[nj] = w;
  }

  const float* relw = relS + wid * 176;
  const float scl = 0.20412414523193154f;

  #pragma unroll
  for (int mi = 0; mi < 4; ++mi) {
    f32x4 sacc[4];
    #pragma unroll
    for (int nj = 0; nj < 4; ++nj)
      sacc[nj] = __builtin_amdgcn_mfma_f32_16x16x32_bf16(kf[nj], qf[mi],
                                                         (f32x4){0, 0, 0, 0}, 0, 0, 0);
    const int i = mi * 16 + fr;
    const int r1 = i / 7, c1 = i - r1 * 7;
    const int base13 = (r1 + 6) * 13 + (c1 + 6);
    int ri = 0;
    if (SHIFT) {
      const int hi2 = hblk * 7 + r1, wi2 = wblk * 7 + c1;
      ri = (hi2 < 49 ? 0 : (hi2 < 53 ? 1 : 2)) * 3 + (wi2 < 49 ? 0 : (wi2 < 53 ? 1 : 2));
    }
    float p[16];
    float mx = -1e30f;
    #pragma unroll
    for (int nj = 0; nj < 4; ++nj) {
      #pragma unroll
      for (int r = 0; r < 4; ++r) {
        const int j = nj * 16 + fg * 4 + r;
        int idx = base13 - (int)((joffPk[nj] >> (r * 8)) & 0xff);
        idx = min(max(idx, 0), 168);
        float v = sacc[nj][r] * scl + relw[idx];
        if (SHIFT) {
          const int rj = (jregPk[nj >> 1] >> (((nj & 1) * 4 + r) * 4)) & 0xf;
          v = (ri != rj) ? v - 100.f : v;
        }
        v = (j < 49) ? v : -1e30f;
        p[nj * 4 + r] = v;
        mx = fmaxf(mx, v);
      }
    }
    mx = fmaxf(mx, __shfl_xor(mx, 16));
    mx = fmaxf(mx, __shfl_xor(mx, 32));
    float sum = 0.f;
    #pragma unroll
    for (int e = 0; e < 16; ++e) { p[e] = __expf(p[e] - mx); sum += p[e]; }
    sum += __shfl_xor(sum, 16);
    sum += __shfl_xor(sum, 32);
    const float inv = 1.f / sum;
    short8 pb[2];
    #pragma unroll
    for (int ks = 0; ks < 2; ++ks) {
      u32 w[4];
      #pragma unroll
      for (int half = 0; half < 2; ++half) {
        const int nj = 2 * ks + half;
        w[half * 2 + 0] = pk_bf16(p[nj * 4 + 0] * inv, p[nj * 4 + 1] * inv);
        w[half * 2 + 1] = pk_bf16(p[nj * 4 + 2] * inv, p[nj * 4 + 3] * inv);
      }
      pb[ks] = *(short8*)w;
    }
    f32x4 o0 = {0, 0, 0, 0}, o1 = {0, 0, 0, 0};
    o0 = __builtin_amdgcn_mfma_f32_16x16x32_bf16(av[0][0], pb[0], o0, 0, 0, 0);
    o0 = __builtin_amdgcn_mfma_f32_16x16x32_bf16(av[0][1], pb[1], o0, 0, 0, 0);
    o1 = __builtin_amdgcn_mfma_f32_16x16x32_bf16(av[1][0], pb[0], o1, 0, 0, 0);
    o1 = __builtin_amdgcn_mfma_f32_16x16x32_bf16(av[1][1], pb[1], o1, 0, 0, 0);
    if (i < 49) {
      u16* orow = outp + ((size_t)win * 49 + i) * C_DIM + h * 24;
      *(uint2*)(orow + fg * 4) =
          make_uint2(pk_bf16(o0[0], o0[1]), pk_bf16(o0[2], o0[3]));
      if (fg < 2)
        *(uint2*)(orow + 16 + fg * 4) =
            make_uint2(pk_bf16(o1[0], o1[1]), pk_bf16(o1[2], o1[3]));
    }
  }
}

// NHWC bf16 tokens -> NCHW f32 (ds2 output)
__global__ __launch_bounds__(256) void transpose_k(
    const u16* __restrict__ in, float* __restrict__ outp)
{
  __shared__ float tile[32][33];
  const int p0 = blockIdx.x * 32;
  const int c0 = blockIdx.y * 32;
  const int tid = threadIdx.x;
  #pragma unroll
  for (int it = 0; it < 2; ++it) {
    const int id = tid + it * 256;
    const int r = id >> 4, c2 = id & 15;
    const u32 v = *(const u32*)(in + (size_t)(p0 + r) * C_DIM + c0 + c2 * 2);
    tile[r][c2 * 2] = bf2f((u16)v);
    tile[r][c2 * 2 + 1] = bf2f(v >> 16);
  }
  __syncthreads();
  const int b = p0 / HW_, pp0 = p0 - b * HW_;
  #pragma unroll
  for (int it = 0; it < 4; ++it) {
    const int id = tid + it * 256;
    const int cl = id >> 5, pl = id & 31;
    outp[((size_t)b * C_DIM + c0 + cl) * HW_ + pp0 + pl] = tile[pl][cl];
  }
}

// NCHW f32 -> token-major bf16
__global__ __launch_bounds__(256) void tok_k(
    const float* __restrict__ in, u16* __restrict__ outp)
{
  __shared__ float tile[32][33];
  const int t0 = blockIdx.x * 32;
  const int c0 = blockIdx.y * 32;
  const int tid = threadIdx.x;
  const int b = t0 / HW_, p0 = t0 - b * HW_;
  #pragma unroll
  for (int it = 0; it < 4; ++it) {
    const int id = tid + it * 256;
    const int cl = id >> 5, pl = id & 31;
    tile[cl][pl] = in[((size_t)b * C_DIM + c0 + cl) * HW_ + p0 + pl];
  }
  __syncthreads();
  #pragma unroll
  for (int it = 0; it < 4; ++it) {
    const int id = tid + it * 256;
    const int r = id >> 5, cc = id & 31;
    outp[(size_t)(t0 + r) * C_DIM + c0 + cc] = f2bf(tile[cc][r]);
  }
}

// all weights f32 -> bf16 wbf blob (one launch); conv weights re-laid im2col
__global__ __launch_bounds__(256) void cvtall_k(
    const float* __restrict__ qkv_w, const float* __restrict__ fc1_w,
    const float* __restrict__ fc2_w, const float* __restrict__ attn_pw,
    const float* __restrict__ proj_w, const float* __restrict__ c1_w,
    const float* __restrict__ c2_w, u16* __restrict__ wbf)
{
  const int i = blockIdx.x * 256 + threadIdx.x;
  const int off1 = SZ_QKV, off2 = off1 + SZ_FC1, off3 = off2 + SZ_FC2,
            off4 = off3 + SZ_PW, off5 = off4 + SZ_PROJ, off6 = off5 + SZ_C1R,
            off7 = off6 + SZ_C2R;
  if (i >= off7) return;
  float v;
  if (i < off1) v = qkv_w[i];
  else if (i < off2) v = fc1_w[i - off1];
  else if (i < off3) v = fc2_w[i - off2];
  else if (i < off4) v = attn_pw[i - off3];
  else if (i < off5) v = proj_w[i - off4];
  else if (i < off6) {
    const int e = i - off5;
    const int n = e / 1728, kkk = e - n * 1728;
    const int s = kkk / C_DIM, ic = kkk - s * C_DIM;
    v = c1_w[((size_t)n * C_DIM + ic) * 9 + s];
  } else {
    const int e = i - off6;
    const int n = e / 1728, kkk = e - n * 1728;
    const int s = kkk / C_DIM, ic = kkk - s * C_DIM;
    v = (n < 96) ? c2_w[((size_t)n * C_DIM + ic) * 9 + s] : 0.f;
  }
  wbf[i] = f2bf(v);
}

// ---------------------------------------------------------------------------
extern "C" void kernel_launch(void* const* d_in, const int* in_sizes, int n_in,
                              void* d_out, int out_size, void* d_ws, size_t ws_size,
                              hipStream_t stream)
{
  const float* x       = (const float*)d_in[0];
  const float* pos     = (const float*)d_in[1];
  const float* proj_w  = (const float*)d_in[2];
  const float* proj_b  = (const float*)d_in[3];
  const float* pe_g    = (const float*)d_in[4];
  const float* pe_b    = (const float*)d_in[5];
  const float* n1_g    = (const float*)d_in[6];
  const float* n1_b    = (const float*)d_in[7];
  const float* qkv_w   = (const float*)d_in[8];
  const float* qkv_b   = (const float*)d_in[9];
  const float* attn_pw = (const float*)d_in[10];
  const float* attn_pb = (const float*)d_in[11];
  const float* rel_tab = (const float*)d_in[12];
  const float* n2_g    = (const float*)d_in[13];
  const float* n2_b    = (const float*)d_in[14];
  const float* fc1_w   = (const float*)d_in[15];
  const float* fc1_b   = (const float*)d_in[16];
  const float* fc2_w   = (const float*)d_in[17];
  const float* fc2_b   = (const float*)d_in[18];
  const float* c1_w    = (const float*)d_in[19];
  const float* c1_b    = (const float*)d_in[20];
  const float* bn1_g   = (const float*)d_in[21];
  const float* bn1_b   = (const float*)d_in[22];
  const float* bn1_m   = (const float*)d_in[23];
  const float* bn1_v   = (const float*)d_in[24];
  const float* c2_w    = (const float*)d_in[25];
  const float* c2_b    = (const float*)d_in[26];
  const float* bn2_g   = (const float*)d_in[27];
  const float* bn2_b   = (const float*)d_in[28];
  const float* bn2_m   = (const float*)d_in[29];
  const float* bn2_v   = (const float*)d_in[30];
  float* out = (float*)d_out;

  // ws layout: act (19.3MB) | big16 (77MB) | xln (19.3MB) = 115.6MB
  const size_t ACTB = (size_t)NTOK * C_DIM * 2;   // 19,267,584 B
  const size_t BIGB = (size_t)NTOK * 768 * 2;     // 77,070,336 B
  char* ws = (char*)d_ws;
  u16* act   = (u16*)ws;
  u16* big16 = (u16*)(ws + ACTB);
  u16* xln   = (u16*)(ws + ACTB + BIGB);
  u16* attn_out = (u16*)d_out;
  u16* wbf = (u16*)((char*)d_out + (size_t)CONV_OUT_SZ * 4);

  const size_t O_QKV = 0;
  const size_t O_FC1 = O_QKV + SZ_QKV;
  const size_t O_FC2 = O_FC1 + SZ_FC1;
  const size_t O_PW  = O_FC2 + SZ_FC2;
  const size_t O_PROJ= O_PW  + SZ_PW;
  const size_t O_C1  = O_PROJ+ SZ_PROJ;
  const size_t O_C2  = O_C1  + SZ_C1R;

  const dim3 blk(256);

  const int cvtall_n = SZ_QKV + SZ_FC1 + SZ_FC2 + SZ_PW + SZ_PROJ + SZ_C1R + SZ_C2R;
  cvtall_k<<<(cvtall_n + 255) / 256, blk, 0, stream>>>(
      qkv_w, fc1_w, fc2_w, attn_pw, proj_w, c1_w, c2_w, wbf);

  tok_k<<<dim3(1568, 6), blk, 0, stream>>>(x, xln);
  gmm64<0><<<dim3(784), blk, 0, stream>>>(
      xln, wbf + O_PROJ, proj_b, big16, NTOK, 192, 192, 3, 0);
  ln_k<<<12544, blk, 0, stream>>>(big16, act, pe_g, pe_b, pos, 0, 0);

  for (int i = 0; i < 4; ++i) {
    const int shift = (i & 1) ? 3 : 0;
    ln_k<<<12544, blk, 0, stream>>>(act, xln, n1_g + i * 192, n1_b + i * 192,
                                    nullptr, 1, shift);
    // qkv: N-persistent (A-panel read once, 9 n-subtiles from local L2)
    gmm64<0><<<dim3(784), blk, 0, stream>>>(
        xln, wbf + O_QKV + (size_t)i * 576 * 192, qkv_b + i * 576, big16,
        NTOK, 576, 192, 9, 0);
    if (shift)
      attn_m<3><<<2048, blk, 0, stream>>>(big16, attn_out, rel_tab + i * 169 * 8);
    else
      attn_m<0><<<2048, blk, 0, stream>>>(big16, attn_out, rel_tab + i * 169 * 8);
    gmm64<6><<<dim3(784), blk, 0, stream>>>(
        attn_out, wbf + O_PW + (size_t)i * 192 * 192, attn_pb + i * 192, act,
        NTOK, 192, 192, 3, shift);
    ln_k<<<12544, blk, 0, stream>>>(act, xln, n2_g + i * 192, n2_b + i * 192,
                                    nullptr, 0, 0);
    // FFN: N-persistent fc1 (12 subtiles, gelu) and fc2 (3 subtiles, RMW)
    gmm64<1><<<dim3(784), blk, 0, stream>>>(
        xln, wbf + O_FC1 + (size_t)i * 768 * 192, fc1_b + i * 768, big16,
        NTOK, 768, 192, 12, 0);
    gmm64<2><<<dim3(784), blk, 0, stream>>>(
        big16, wbf + O_FC2 + (size_t)i * 192 * 768, fc2_b + i * 192, act,
        NTOK, 192, 768, 3, 0);
  }

  // conv head (r20 structure): conv1 gathers act (bf16) directly
  gmm<1, 3><<<dim3(392 * 3), blk, 0, stream>>>(
      act, wbf + O_C1, c1_b, big16, NTOK, 192, 1728, 3, bn1_g, bn1_b, bn1_m, bn1_v, 0);
  gmm<1, 4><<<dim3(392 * 2), blk, 0, stream>>>(
      big16, wbf + O_C2, c2_b, out, NTOK, 96, 1728, 2, bn2_g, bn2_b, bn2_m, bn2_v, 0);
  transpose_k<<<dim3(1568, 6), blk, 0, stream>>>(act, out + CONV_OUT_SZ);
}

// Round 22
// 828.033 us; speedup vs baseline: 1.1562x; 1.1562x over previous
//
#include <hip/hip_runtime.h>
#include <math.h>

typedef unsigned short u16;
typedef unsigned int u32;
typedef __attribute__((ext_vector_type(8))) short short8;
typedef __attribute__((ext_vector_type(4))) float f32x4;

#define IMG 56
#define HW_ 3136
#define NTOK 50176
#define C_DIM 192
#define CONV_OUT_SZ 4816896  /* 16*96*3136 floats */

#define SZ_QKV (4*576*192)
#define SZ_FC1 (4*768*192)
#define SZ_FC2 (4*192*768)
#define SZ_PW  (4*192*192)
#define SZ_PROJ (192*192)
#define SZ_C1R (192*1728)
#define SZ_C2R (128*1728)

__device__ inline float bf2f(u16 v) {
  u32 u = ((u32)v) << 16; float f; __builtin_memcpy(&f, &u, 4); return f;
}
__device__ inline u16 f2bf(float f) {
  u32 u; __builtin_memcpy(&u, &f, 4);
  u += 0x7FFF + ((u >> 16) & 1);
  return (u16)(u >> 16);
}
__device__ inline void glds16(const u16* g, u16* l) {
  __builtin_amdgcn_global_load_lds((const __attribute__((address_space(1))) u32*)g,
                                   (__attribute__((address_space(3))) u32*)l, 16, 0, 0);
}
__device__ inline u32 pk_bf16(float a, float b) {
  u32 r;
  asm("v_cvt_pk_bf16_f32 %0, %1, %2" : "=v"(r) : "v"(a), "v"(b));
  return r;
}

// XCD-aware decode: flat f -> (m-block, n-block) with all NB n-blocks of one
// m-panel on the SAME XCD (f % 8 == m-block % 8) and adjacent in issue order.
__device__ inline void xcd_decode(int f, int NB, int& mb, int& nb) {
  const int ml = f & 7;
  const int rest = f >> 3;
  nb = rest % NB;
  mb = (rest / NB) * 8 + ml;
}

// ---------------------------------------------------------------------------
// MFMA bf16 GEMM (r6-proven K-loop): BM=128, BN=64, BK=64, single-buffered
// 24KB LDS, 4 waves (2x2), 16x16x32 MFMA.  1-D grid, XCD-aware (m,n) decode.
// EPI: 0 store bf16, 1 gelu->bf16, 2 +=bf16 (vector RMW), 3 BN+relu->bf16 NHWC,
//      4 BN+relu->f32 NCHW (guard c<N),
//      6 win-reverse + roll(+shiftp) +=bf16 NHWC act (vector RMW per row).
// ---------------------------------------------------------------------------
template<int AMODE, int EPI>
__global__ __launch_bounds__(256) void gmm(
    const u16* __restrict__ A, const u16* __restrict__ W,
    const float* __restrict__ bias, void* __restrict__ Cout,
    int M, int N, int K, int NB,
    const float* __restrict__ bg, const float* __restrict__ bb,
    const float* __restrict__ bm, const float* __restrict__ bv, int shiftp)
{
  __shared__ u16 As[128 * 64];
  __shared__ u16 Bs[64 * 64];
  const int tid = threadIdx.x;
  int mb, nb;
  xcd_decode(blockIdx.x, NB, mb, nb);
  const int m0 = mb * 128, n0 = nb * 64;
  const int lane = tid & 63, wid = tid >> 6;
  const int wm = (wid >> 1) * 64, wn = (wid & 1) * 32;
  const int fr = lane & 15, fg = lane >> 4;
  f32x4 acc[4][2] = {};

  // K-invariant geometry for the conv gather (static indexing -> registers)
  const u16* rowp0; const u16* rowp1; const u16* rowp2; const u16* rowp3;
  int ry0, ry1, ry2, ry3, rx0, rx1, rx2, rx3;
  if (AMODE == 1) {
    #pragma unroll
    for (int it = 0; it < 4; ++it) {
      const int g = it * 256 + tid;
      const int row = g >> 3;
      const int m = m0 + row;
      const int b = m / HW_, pp = m - b * HW_;
      const int y = pp / IMG, x = pp - (pp / IMG) * IMG;
      const u16* rp = A + ((size_t)(b * HW_ + y * IMG + x)) * C_DIM;
      if (it == 0) { rowp0 = rp; ry0 = y; rx0 = x; }
      else if (it == 1) { rowp1 = rp; ry1 = y; rx1 = x; }
      else if (it == 2) { rowp2 = rp; ry2 = y; rx2 = x; }
      else { rowp3 = rp; ry3 = y; rx3 = x; }
    }
  }

  for (int kc = 0; kc < K; kc += 64) {
    #pragma unroll
    for (int it = 0; it < 2; ++it) {
      const int g = it * 256 + tid;
      const int row = g >> 3, cb = (g & 7) << 4;
      const int sc = cb ^ ((row & 7) << 4);
      glds16(W + (size_t)(n0 + row) * K + kc + (sc >> 1), Bs + g * 8);
    }
    if (AMODE == 0) {
      #pragma unroll
      for (int it = 0; it < 4; ++it) {
        const int g = it * 256 + tid;
        const int row = g >> 3, cb = (g & 7) << 4;
        const int sc = cb ^ ((row & 7) << 4);
        glds16(A + (size_t)(m0 + row) * K + kc + (sc >> 1), As + g * 8);
      }
    } else {  // im2col gather: only (s,ic,dy,dx) depend on kc
      #pragma unroll
      for (int it = 0; it < 4; ++it) {
        const int g = it * 256 + tid;
        const int row = g >> 3, cb = (g & 7) << 4;
        const int kg = kc + (cb >> 1);
        const int s = kg / C_DIM, ic = kg - s * C_DIM;
        const int dy = s / 3 - 1, dx = s % 3 - 1;
        const u16* rp = (it == 0) ? rowp0 : (it == 1) ? rowp1 : (it == 2) ? rowp2 : rowp3;
        const int y = (it == 0) ? ry0 : (it == 1) ? ry1 : (it == 2) ? ry2 : ry3;
        const int x = (it == 0) ? rx0 : (it == 1) ? rx1 : (it == 2) ? rx2 : rx3;
        const int yy = y + dy, xx = x + dx;
        short8 v = {0, 0, 0, 0, 0, 0, 0, 0};
        if ((unsigned)yy < IMG && (unsigned)xx < IMG)
          v = *(const short8*)(rp + (dy * IMG + dx) * C_DIM + ic);
        *(short8*)(As + row * 64 + ((cb ^ ((row & 7) << 4)) >> 1)) = v;
      }
    }
    __syncthreads();
    #pragma unroll
    for (int ks = 0; ks < 2; ++ks) {
      const int kb = ks * 64 + fg * 16;
      short8 af[4], bfv[2];
      #pragma unroll
      for (int i = 0; i < 4; ++i) {
        const int row = wm + i * 16 + fr;
        af[i] = *(const short8*)(As + ((row * 128 + (kb ^ ((row & 7) << 4))) >> 1));
      }
      #pragma unroll
      for (int j = 0; j < 2; ++j) {
        const int row = wn + j * 16 + fr;
        bfv[j] = *(const short8*)(Bs + ((row * 128 + (kb ^ ((row & 7) << 4))) >> 1));
      }
      #pragma unroll
      for (int i = 0; i < 4; ++i)
        #pragma unroll
        for (int j = 0; j < 2; ++j)
          acc[i][j] = __builtin_amdgcn_mfma_f32_16x16x32_bf16(af[i], bfv[j], acc[i][j], 0, 0, 0);
    }
    __syncthreads();
  }

  // ---- epilogue. C/D: col = lane&15, row = fg*4 + reg.
  const int c0 = n0 + wn + fr;
  const int c1i = (EPI == 4) ? min(c0 + 16, N - 1) : (c0 + 16);
  const float bias0 = bias[c0], bias1 = bias[c1i];
  float s0 = 0.f, h0 = 0.f, s1 = 0.f, h1 = 0.f;
  if (EPI == 3 || EPI == 4) {
    s0 = bg[c0] * rsqrtf(bv[c0] + 1e-5f); h0 = bb[c0] - bm[c0] * s0;
    s1 = bg[c1i] * rsqrtf(bv[c1i] + 1e-5f); h1 = bb[c1i] - bm[c1i] * s1;
  }

  if (EPI == 0 || EPI == 1 || EPI == 2 || EPI == 6) {
    #pragma unroll
    for (int i = 0; i < 4; ++i) {
      #pragma unroll
      for (int r = 0; r < 4; ++r) {
        const int ml = wm + i * 16 + fg * 4 + r;
        #pragma unroll
        for (int j = 0; j < 2; ++j) {
          float v = acc[i][j][r] + (j ? bias1 : bias0);
          if (EPI == 1) v = 0.5f * v * (1.f + erff(v * 0.70710678118f));
          const int cl = wn + j * 16 + fr;
          As[ml * 64 + ((cl & 7) | ((((cl >> 3) ^ ml) & 7) << 3))] = f2bf(v);
        }
      }
    }
    __syncthreads();
    #pragma unroll
    for (int p = 0; p < 4; ++p) {
      const int id = p * 256 + tid;
      const int ml = id >> 3, grp = id & 7;
      const int pg = (grp ^ ml) & 7;
      const short8 vv = *(const short8*)(As + ml * 64 + pg * 8);
      if (EPI == 0 || EPI == 1) {
        *(short8*)((u16*)Cout + (size_t)(m0 + ml) * N + n0 + grp * 8) = vv;
      } else {
        size_t dstoff;
        if (EPI == 2) {
          dstoff = (size_t)(m0 + ml) * N + n0 + grp * 8;
        } else {
          const int m = m0 + ml;
          const int wno = m / 49, within = m - wno * 49;
          const int b2 = wno >> 6, wb3 = wno & 63;
          const int wr = within / 7, wc = within - wr * 7;
          int y2 = (wb3 >> 3) * 7 + wr + shiftp; if (y2 >= IMG) y2 -= IMG;
          int x2 = (wb3 & 7) * 7 + wc + shiftp; if (x2 >= IMG) x2 -= IMG;
          dstoff = ((size_t)(b2 * HW_ + y2 * IMG + x2)) * C_DIM + n0 + grp * 8;
        }
        u16* p8 = (u16*)Cout + dstoff;
        const short8 old = *(const short8*)p8;
        const u16* av_ = (const u16*)&vv;
        const u16* ov_ = (const u16*)&old;
        u32 res[4];
        #pragma unroll
        for (int e = 0; e < 4; ++e)
          res[e] = pk_bf16(bf2f(ov_[2 * e]) + bf2f(av_[2 * e]),
                           bf2f(ov_[2 * e + 1]) + bf2f(av_[2 * e + 1]));
        *(short8*)p8 = *(const short8*)res;
      }
    }
  } else {
    #pragma unroll
    for (int i = 0; i < 4; ++i) {
      #pragma unroll
      for (int r = 0; r < 4; ++r) {
        const int m = m0 + wm + i * 16 + fg * 4 + r;
        #pragma unroll
        for (int j = 0; j < 2; ++j) {
          const int c = c0 + j * 16;
          float v = acc[i][j][r] + (j ? bias1 : bias0);
          v = v * (j ? s1 : s0) + (j ? h1 : h0);
          v = fmaxf(v, 0.f);
          if (EPI == 3) {
            ((u16*)Cout)[(size_t)m * N + c] = f2bf(v);
          } else {
            if (c < N) {
              const int b = m / HW_, pp = m - b * HW_;
              ((float*)Cout)[((size_t)b * N + c) * HW_ + pp] = v;
            }
          }
        }
      }
    }
  }
}

// ---------------------------------------------------------------------------
// BM=64 variant (patch EPI0, proj EPI6), 1-D grid + XCD-aware decode.
// ---------------------------------------------------------------------------
template<int EPI>
__global__ __launch_bounds__(256) void gmm64(
    const u16* __restrict__ A, const u16* __restrict__ W,
    const float* __restrict__ bias, void* __restrict__ Cout,
    int M, int N, int K, int NB, int shiftp)
{
  __shared__ u16 As[64 * 64];
  __shared__ u16 Bs[64 * 64];
  const int tid = threadIdx.x;
  int mb, nb;
  xcd_decode(blockIdx.x, NB, mb, nb);
  const int m0 = mb * 64, n0 = nb * 64;
  const int lane = tid & 63, wid = tid >> 6;
  const int wm = (wid >> 1) * 32, wn = (wid & 1) * 32;
  const int fr = lane & 15, fg = lane >> 4;
  f32x4 acc[2][2] = {};

  for (int kc = 0; kc < K; kc += 64) {
    #pragma unroll
    for (int it = 0; it < 2; ++it) {
      const int g = it * 256 + tid;
      const int row = g >> 3, cb = (g & 7) << 4;
      const int sc = cb ^ ((row & 7) << 4);
      glds16(W + (size_t)(n0 + row) * K + kc + (sc >> 1), Bs + g * 8);
      glds16(A + (size_t)(m0 + row) * K + kc + (sc >> 1), As + g * 8);
    }
    __syncthreads();
    #pragma unroll
    for (int ks = 0; ks < 2; ++ks) {
      const int kb = ks * 64 + fg * 16;
      short8 af[2], bfv[2];
      #pragma unroll
      for (int i = 0; i < 2; ++i) {
        const int row = wm + i * 16 + fr;
        af[i] = *(const short8*)(As + ((row * 128 + (kb ^ ((row & 7) << 4))) >> 1));
      }
      #pragma unroll
      for (int j = 0; j < 2; ++j) {
        const int row = wn + j * 16 + fr;
        bfv[j] = *(const short8*)(Bs + ((row * 128 + (kb ^ ((row & 7) << 4))) >> 1));
      }
      #pragma unroll
      for (int i = 0; i < 2; ++i)
        #pragma unroll
        for (int j = 0; j < 2; ++j)
          acc[i][j] = __builtin_amdgcn_mfma_f32_16x16x32_bf16(af[i], bfv[j], acc[i][j], 0, 0, 0);
    }
    __syncthreads();
  }

  const int c0 = n0 + wn + fr;
  const float bias0 = bias[c0], bias1 = bias[c0 + 16];
  #pragma unroll
  for (int i = 0; i < 2; ++i) {
    #pragma unroll
    for (int r = 0; r < 4; ++r) {
      const int ml = wm + i * 16 + fg * 4 + r;
      #pragma unroll
      for (int j = 0; j < 2; ++j) {
        const float v = acc[i][j][r] + (j ? bias1 : bias0);
        const int cl = wn + j * 16 + fr;
        As[ml * 64 + ((cl & 7) | ((((cl >> 3) ^ ml) & 7) << 3))] = f2bf(v);
      }
    }
  }
  __syncthreads();
  #pragma unroll
  for (int p = 0; p < 2; ++p) {
    const int id = p * 256 + tid;
    const int ml = id >> 3, grp = id & 7;
    const int pg = (grp ^ ml) & 7;
    const short8 vv = *(const short8*)(As + ml * 64 + pg * 8);
    if (EPI == 0) {
      *(short8*)((u16*)Cout + (size_t)(m0 + ml) * N + n0 + grp * 8) = vv;
    } else {  // EPI 6: win-reverse + roll scatter-add (channels contiguous)
      const int m = m0 + ml;
      const int wno = m / 49, within = m - wno * 49;
      const int b2 = wno >> 6, wb3 = wno & 63;
      const int wr = within / 7, wc = within - wr * 7;
      int y2 = (wb3 >> 3) * 7 + wr + shiftp; if (y2 >= IMG) y2 -= IMG;
      int x2 = (wb3 & 7) * 7 + wc + shiftp; if (x2 >= IMG) x2 -= IMG;
      const size_t dstoff = ((size_t)(b2 * HW_ + y2 * IMG + x2)) * C_DIM + n0 + grp * 8;
      u16* p8 = (u16*)Cout + dstoff;
      const short8 old = *(const short8*)p8;
      const u16* av_ = (const u16*)&vv;
      const u16* ov_ = (const u16*)&old;
      u32 res[4];
      #pragma unroll
      for (int e = 0; e < 4; ++e)
        res[e] = pk_bf16(bf2f(ov_[2 * e]) + bf2f(av_[2 * e]),
                         bf2f(ov_[2 * e + 1]) + bf2f(av_[2 * e + 1]));
      *(short8*)p8 = *(const short8*)res;
    }
  }
}

// ---------------------------------------------------------------------------
// LayerNorm over C=192, bf16 in / bf16 out, wave-per-token (4 tokens/block).
// ---------------------------------------------------------------------------
__global__ __launch_bounds__(256) void ln_k(
    const u16* __restrict__ in, u16* __restrict__ outp,
    const float* __restrict__ g, const float* __restrict__ bta,
    const float* __restrict__ pos, int winpart, int shift)
{
  const int t = blockIdx.x * 4 + (threadIdx.x >> 6);
  const int lane = threadIdx.x & 63;
  const uint2* row = (const uint2*)(in + (size_t)t * C_DIM);
  uint2 w = make_uint2(0, 0);
  if (lane < 48) w = row[lane];
  const float v0 = bf2f((u16)w.x), v1 = bf2f(w.x >> 16);
  const float v2 = bf2f((u16)w.y), v3 = bf2f(w.y >> 16);
  float s = v0 + v1 + v2 + v3;
  float ss = v0 * v0 + v1 * v1 + v2 * v2 + v3 * v3;
  #pragma unroll
  for (int off = 32; off > 0; off >>= 1) {
    s += __shfl_xor(s, off);
    ss += __shfl_xor(ss, off);
  }
  const float mean = s * (1.f / 192.f);
  const float inv = rsqrtf(ss * (1.f / 192.f) - mean * mean + 1e-5f);
  const int b = t / HW_, pp = t - b * HW_;
  size_t obase;
  if (winpart) {
    const int y = pp / IMG, x = pp - (pp / IMG) * IMG;
    int yr = y - shift; if (yr < 0) yr += IMG;
    int xs = x - shift; if (xs < 0) xs += IMG;
    const int win = b * 64 + (yr / 7) * 8 + (xs / 7);
    const int within = (yr % 7) * 7 + (xs % 7);
    obase = ((size_t)win * 49 + within) * C_DIM;
  } else {
    obase = (size_t)t * C_DIM;
  }
  if (lane < 48) {
    const float4 gg = *(const float4*)(g + lane * 4);
    const float4 bb = *(const float4*)(bta + lane * 4);
    float p0 = 0.f, p1 = 0.f, p2 = 0.f, p3 = 0.f;
    if (pos) {
      const float4 pv = *(const float4*)(pos + (size_t)pp * C_DIM + lane * 4);
      p0 = pv.x; p1 = pv.y; p2 = pv.z; p3 = pv.w;
    }
    const float r0 = (v0 - mean) * inv * gg.x + bb.x + p0;
    const float r1 = (v1 - mean) * inv * gg.y + bb.y + p1;
    const float r2 = (v2 - mean) * inv * gg.z + bb.z + p2;
    const float r3 = (v3 - mean) * inv * gg.w + bb.w + p3;
    ((uint2*)(outp + obase))[lane] = make_uint2(pk_bf16(r0, r1), pk_bf16(r2, r3));
  }
}

// ---------------------------------------------------------------------------
// MFMA window attention, swapped-QK^T + sigma-order PV (P stays in registers).
// ---------------------------------------------------------------------------
template<int SHIFT>
__global__ __launch_bounds__(256) void attn_m(
    const u16* __restrict__ qkv, u16* __restrict__ outp,
    const float* __restrict__ rel)
{
  __shared__ u16 VT[128 * 64];
  __shared__ float relS[4 * 176 + 16];
  const int tid = threadIdx.x;
  const int wid = tid >> 6, lane = tid & 63;
  const int fr = lane & 15, fg = lane >> 4;
  const int win = blockIdx.x >> 1;
  const int hb = blockIdx.x & 1;
  const int h = hb * 4 + wid;
  const u16* wbase = qkv + (size_t)win * 49 * 576;

  {
    u32* vz = (u32*)VT;
    #pragma unroll
    for (int it = 0; it < 16; ++it) vz[it * 256 + tid] = 0;
  }
  for (int id = tid; id < 169 * 4; id += 256) {
    const int hl = id & 3, ridx = id >> 2;
    relS[hl * 176 + ridx] = rel[ridx * 8 + hb * 4 + hl];
  }
  __syncthreads();
  for (int id = tid; id < 49 * 24; id += 256) {
    const int j = id / 24, dq = id - (id / 24) * 24;
    const int dd = dq * 4;
    const uint2 v = *(const uint2*)(wbase + j * 576 + 384 + hb * 96 + dd);
    const u16* pv = (const u16*)&v;
    const int wpr = dd / 24, dl = dd - wpr * 24;
    #pragma unroll
    for (int e = 0; e < 4; ++e) {
      const int row = wpr * 32 + dl + e;
      VT[(row * 128 + ((j * 2) ^ (((row >> 2) & 7) << 4))) >> 1] = pv[e];
    }
  }
  __syncthreads();

  short8 qf[4], kf[4];
  #pragma unroll
  for (int t = 0; t < 4; ++t) {
    const int row = t * 16 + fr;
    if (fg < 3) {
      qf[t] = *(const short8*)(wbase + row * 576 + h * 24 + fg * 8);
      kf[t] = *(const short8*)(wbase + row * 576 + 192 + h * 24 + fg * 8);
    } else {
      qf[t] = (short8){0, 0, 0, 0, 0, 0, 0, 0};
      kf[t] = (short8){0, 0, 0, 0, 0, 0, 0, 0};
    }
  }

  short8 av[2][2];
  #pragma unroll
  for (int db = 0; db < 2; ++db) {
    const int row = wid * 32 + db * 16 + fr;
    const int swz = ((row >> 2) & 7) << 4;
    #pragma unroll
    for (int ks = 0; ks < 2; ++ks) {
      const uint2 lo = *(const uint2*)((const char*)VT + row * 128 + (((2 * ks) * 32 + fg * 8) ^ swz));
      const uint2 hi = *(const uint2*)((const char*)VT + row * 128 + (((2 * ks + 1) * 32 + fg * 8) ^ swz));
      u32 w[4] = {lo.x, lo.y, hi.x, hi.y};
      av[db][ks] = *(short8*)w;
    }
  }

  const int wb2 = win & 63;
  const int hblk = wb2 >> 3, wblk = wb2 & 7;

  u32 joffPk[4];
  u32 jregPk[2] = {0, 0};
  #pragma unroll
  for (int nj = 0; nj < 4; ++nj) {
    u32 w = 0;
    #pragma unroll
    for (int r = 0; r < 4; ++r) {
      const int j = nj * 16 + fg * 4 + r;
      const int r2 = j / 7, c2 = j - r2 * 7;
      w |= (u32)(r2 * 13 + c2) << (r * 8);
      if (SHIFT) {
        const int hj = hblk * 7 + r2, wj = wblk * 7 + c2;
        const int rj = (hj < 49 ? 0 : (hj < 53 ? 1 : 2)) * 3 + (wj < 49 ? 0 : (wj < 53 ? 1 : 2));
        jregPk[nj >> 1] |= (u32)rj << (((nj & 1) * 4 + r) * 4);
      }
    }
    joffPk[nj] = w;
  }

  const float* relw = relS + wid * 176;
  const float scl = 0.20412414523193154f;

  #pragma unroll
  for (int mi = 0; mi < 4; ++mi) {
    f32x4 sacc[4];
    #pragma unroll
    for (int nj = 0; nj < 4; ++nj)
      sacc[nj] = __builtin_amdgcn_mfma_f32_16x16x32_bf16(kf[nj], qf[mi],
                                                         (f32x4){0, 0, 0, 0}, 0, 0, 0);
    const int i = mi * 16 + fr;
    const int r1 = i / 7, c1 = i - r1 * 7;
    const int base13 = (r1 + 6) * 13 + (c1 + 6);
    int ri = 0;
    if (SHIFT) {
      const int hi2 = hblk * 7 + r1, wi2 = wblk * 7 + c1;
      ri = (hi2 < 49 ? 0 : (hi2 < 53 ? 1 : 2)) * 3 + (wi2 < 49 ? 0 : (wi2 < 53 ? 1 : 2));
    }
    float p[16];
    float mx = -1e30f;
    #pragma unroll
    for (int nj = 0; nj < 4; ++nj) {
      #pragma unroll
      for (int r = 0; r < 4; ++r) {
        const int j = nj * 16 + fg * 4 + r;
        int idx = base13 - (int)((joffPk[nj] >> (r * 8)) & 0xff);
        idx = min(max(idx, 0), 168);
        float v = sacc[nj][r] * scl + relw[idx];
        if (SHIFT) {
          const int rj = (jregPk[nj >> 1] >> (((nj & 1) * 4 + r) * 4)) & 0xf;
          v = (ri != rj) ? v - 100.f : v;
        }
        v = (j < 49) ? v : -1e30f;
        p[nj * 4 + r] = v;
        mx = fmaxf(mx, v);
      }
    }
    mx = fmaxf(mx, __shfl_xor(mx, 16));
    mx = fmaxf(mx, __shfl_xor(mx, 32));
    float sum = 0.f;
    #pragma unroll
    for (int e = 0; e < 16; ++e) { p[e] = __expf(p[e] - mx); sum += p[e]; }
    sum += __shfl_xor(sum, 16);
    sum += __shfl_xor(sum, 32);
    const float inv = 1.f / sum;
    short8 pb[2];
    #pragma unroll
    for (int ks = 0; ks < 2; ++ks) {
      u32 w[4];
      #pragma unroll
      for (int half = 0; half < 2; ++half) {
        const int nj = 2 * ks + half;
        w[half * 2 + 0] = pk_bf16(p[nj * 4 + 0] * inv, p[nj * 4 + 1] * inv);
        w[half * 2 + 1] = pk_bf16(p[nj * 4 + 2] * inv, p[nj * 4 + 3] * inv);
      }
      pb[ks] = *(short8*)w;
    }
    f32x4 o0 = {0, 0, 0, 0}, o1 = {0, 0, 0, 0};
    o0 = __builtin_amdgcn_mfma_f32_16x16x32_bf16(av[0][0], pb[0], o0, 0, 0, 0);
    o0 = __builtin_amdgcn_mfma_f32_16x16x32_bf16(av[0][1], pb[1], o0, 0, 0, 0);
    o1 = __builtin_amdgcn_mfma_f32_16x16x32_bf16(av[1][0], pb[0], o1, 0, 0, 0);
    o1 = __builtin_amdgcn_mfma_f32_16x16x32_bf16(av[1][1], pb[1], o1, 0, 0, 0);
    if (i < 49) {
      u16* orow = outp + ((size_t)win * 49 + i) * C_DIM + h * 24;
      *(uint2*)(orow + fg * 4) =
          make_uint2(pk_bf16(o0[0], o0[1]), pk_bf16(o0[2], o0[3]));
      if (fg < 2)
        *(uint2*)(orow + 16 + fg * 4) =
            make_uint2(pk_bf16(o1[0], o1[1]), pk_bf16(o1[2], o1[3]));
    }
  }
}

// NHWC bf16 tokens -> NCHW f32 (ds2 output)
__global__ __launch_bounds__(256) void transpose_k(
    const u16* __restrict__ in, float* __restrict__ outp)
{
  __shared__ float tile[32][33];
  const int p0 = blockIdx.x * 32;
  const int c0 = blockIdx.y * 32;
  const int tid = threadIdx.x;
  #pragma unroll
  for (int it = 0; it < 2; ++it) {
    const int id = tid + it * 256;
    const int r = id >> 4, c2 = id & 15;
    const u32 v = *(const u32*)(in + (size_t)(p0 + r) * C_DIM + c0 + c2 * 2);
    tile[r][c2 * 2] = bf2f((u16)v);
    tile[r][c2 * 2 + 1] = bf2f(v >> 16);
  }
  __syncthreads();
  const int b = p0 / HW_, pp0 = p0 - b * HW_;
  #pragma unroll
  for (int it = 0; it < 4; ++it) {
    const int id = tid + it * 256;
    const int cl = id >> 5, pl = id & 31;
    outp[((size_t)b * C_DIM + c0 + cl) * HW_ + pp0 + pl] = tile[pl][cl];
  }
}

// NCHW f32 -> token-major bf16
__global__ __launch_bounds__(256) void tok_k(
    const float* __restrict__ in, u16* __restrict__ outp)
{
  __shared__ float tile[32][33];
  const int t0 = blockIdx.x * 32;
  const int c0 = blockIdx.y * 32;
  const int tid = threadIdx.x;
  const int b = t0 / HW_, p0 = t0 - b * HW_;
  #pragma unroll
  for (int it = 0; it < 4; ++it) {
    const int id = tid + it * 256;
    const int cl = id >> 5, pl = id & 31;
    tile[cl][pl] = in[((size_t)b * C_DIM + c0 + cl) * HW_ + p0 + pl];
  }
  __syncthreads();
  #pragma unroll
  for (int it = 0; it < 4; ++it) {
    const int id = tid + it * 256;
    const int r = id >> 5, cc = id & 31;
    outp[(size_t)(t0 + r) * C_DIM + c0 + cc] = f2bf(tile[cc][r]);
  }
}

// all weights f32 -> bf16 wbf blob (one launch); conv weights re-laid im2col
__global__ __launch_bounds__(256) void cvtall_k(
    const float* __restrict__ qkv_w, const float* __restrict__ fc1_w,
    const float* __restrict__ fc2_w, const float* __restrict__ attn_pw,
    const float* __restrict__ proj_w, const float* __restrict__ c1_w,
    const float* __restrict__ c2_w, u16* __restrict__ wbf)
{
  const int i = blockIdx.x * 256 + threadIdx.x;
  const int off1 = SZ_QKV, off2 = off1 + SZ_FC1, off3 = off2 + SZ_FC2,
            off4 = off3 + SZ_PW, off5 = off4 + SZ_PROJ, off6 = off5 + SZ_C1R,
            off7 = off6 + SZ_C2R;
  if (i >= off7) return;
  float v;
  if (i < off1) v = qkv_w[i];
  else if (i < off2) v = fc1_w[i - off1];
  else if (i < off3) v = fc2_w[i - off2];
  else if (i < off4) v = attn_pw[i - off3];
  else if (i < off5) v = proj_w[i - off4];
  else if (i < off6) {
    const int e = i - off5;
    const int n = e / 1728, kkk = e - n * 1728;
    const int s = kkk / C_DIM, ic = kkk - s * C_DIM;
    v = c1_w[((size_t)n * C_DIM + ic) * 9 + s];
  } else {
    const int e = i - off6;
    const int n = e / 1728, kkk = e - n * 1728;
    const int s = kkk / C_DIM, ic = kkk - s * C_DIM;
    v = (n < 96) ? c2_w[((size_t)n * C_DIM + ic) * 9 + s] : 0.f;
  }
  wbf[i] = f2bf(v);
}

// ---------------------------------------------------------------------------
extern "C" void kernel_launch(void* const* d_in, const int* in_sizes, int n_in,
                              void* d_out, int out_size, void* d_ws, size_t ws_size,
                              hipStream_t stream)
{
  const float* x       = (const float*)d_in[0];
  const float* pos     = (const float*)d_in[1];
  const float* proj_w  = (const float*)d_in[2];
  const float* proj_b  = (const float*)d_in[3];
  const float* pe_g    = (const float*)d_in[4];
  const float* pe_b    = (const float*)d_in[5];
  const float* n1_g    = (const float*)d_in[6];
  const float* n1_b    = (const float*)d_in[7];
  const float* qkv_w   = (const float*)d_in[8];
  const float* qkv_b   = (const float*)d_in[9];
  const float* attn_pw = (const float*)d_in[10];
  const float* attn_pb = (const float*)d_in[11];
  const float* rel_tab = (const float*)d_in[12];
  const float* n2_g    = (const float*)d_in[13];
  const float* n2_b    = (const float*)d_in[14];
  const float* fc1_w   = (const float*)d_in[15];
  const float* fc1_b   = (const float*)d_in[16];
  const float* fc2_w   = (const float*)d_in[17];
  const float* fc2_b   = (const float*)d_in[18];
  const float* c1_w    = (const float*)d_in[19];
  const float* c1_b    = (const float*)d_in[20];
  const float* bn1_g   = (const float*)d_in[21];
  const float* bn1_b   = (const float*)d_in[22];
  const float* bn1_m   = (const float*)d_in[23];
  const float* bn1_v   = (const float*)d_in[24];
  const float* c2_w    = (const float*)d_in[25];
  const float* c2_b    = (const float*)d_in[26];
  const float* bn2_g   = (const float*)d_in[27];
  const float* bn2_b   = (const float*)d_in[28];
  const float* bn2_m   = (const float*)d_in[29];
  const float* bn2_v   = (const float*)d_in[30];
  float* out = (float*)d_out;

  // ws layout: act (19.3MB) | big16 (77MB) | xln (19.3MB) = 115.6MB
  const size_t ACTB = (size_t)NTOK * C_DIM * 2;   // 19,267,584 B
  const size_t BIGB = (size_t)NTOK * 768 * 2;     // 77,070,336 B
  char* ws = (char*)d_ws;
  u16* act   = (u16*)ws;
  u16* big16 = (u16*)(ws + ACTB);
  u16* xln   = (u16*)(ws + ACTB + BIGB);
  u16* attn_out = (u16*)d_out;
  u16* wbf = (u16*)((char*)d_out + (size_t)CONV_OUT_SZ * 4);

  const size_t O_QKV = 0;
  const size_t O_FC1 = O_QKV + SZ_QKV;
  const size_t O_FC2 = O_FC1 + SZ_FC1;
  const size_t O_PW  = O_FC2 + SZ_FC2;
  const size_t O_PROJ= O_PW  + SZ_PW;
  const size_t O_C1  = O_PROJ+ SZ_PROJ;
  const size_t O_C2  = O_C1  + SZ_C1R;

  const dim3 blk(256);

  const int cvtall_n = SZ_QKV + SZ_FC1 + SZ_FC2 + SZ_PW + SZ_PROJ + SZ_C1R + SZ_C2R;
  cvtall_k<<<(cvtall_n + 255) / 256, blk, 0, stream>>>(
      qkv_w, fc1_w, fc2_w, attn_pw, proj_w, c1_w, c2_w, wbf);

  tok_k<<<dim3(1568, 6), blk, 0, stream>>>(x, xln);
  gmm64<0><<<dim3(784 * 3), blk, 0, stream>>>(
      xln, wbf + O_PROJ, proj_b, big16, NTOK, 192, 192, 3, 0);
  ln_k<<<12544, blk, 0, stream>>>(big16, act, pe_g, pe_b, pos, 0, 0);

  for (int i = 0; i < 4; ++i) {
    const int shift = (i & 1) ? 3 : 0;
    ln_k<<<12544, blk, 0, stream>>>(act, xln, n1_g + i * 192, n1_b + i * 192,
                                    nullptr, 1, shift);
    gmm<0, 0><<<dim3(392 * 9), blk, 0, stream>>>(
        xln, wbf + O_QKV + (size_t)i * 576 * 192, qkv_b + i * 576, big16,
        NTOK, 576, 192, 9, nullptr, nullptr, nullptr, nullptr, 0);
    if (shift)
      attn_m<3><<<2048, blk, 0, stream>>>(big16, attn_out, rel_tab + i * 169 * 8);
    else
      attn_m<0><<<2048, blk, 0, stream>>>(big16, attn_out, rel_tab + i * 169 * 8);
    gmm64<6><<<dim3(784 * 3), blk, 0, stream>>>(
        attn_out, wbf + O_PW + (size_t)i * 192 * 192, attn_pb + i * 192, act,
        NTOK, 192, 192, 3, shift);
    ln_k<<<12544, blk, 0, stream>>>(act, xln, n2_g + i * 192, n2_b + i * 192,
                                    nullptr, 0, 0);
    // FFN unchunked: fc1 -> 77MB hidden, fc2 (128-tile, K=768) -> act RMW
    gmm<0, 1><<<dim3(392 * 12), blk, 0, stream>>>(
        xln, wbf + O_FC1 + (size_t)i * 768 * 192, fc1_b + i * 768, big16,
        NTOK, 768, 192, 12, nullptr, nullptr, nullptr, nullptr, 0);
    gmm<0, 2><<<dim3(392 * 3), blk, 0, stream>>>(
        big16, wbf + O_FC2 + (size_t)i * 192 * 768, fc2_b + i * 192, act,
        NTOK, 192, 768, 3, nullptr, nullptr, nullptr, nullptr, 0);
  }

  // conv head: conv1 gathers act (bf16) directly
  gmm<1, 3><<<dim3(392 * 3), blk, 0, stream>>>(
      act, wbf + O_C1, c1_b, big16, NTOK, 192, 1728, 3, bn1_g, bn1_b, bn1_m, bn1_v, 0);
  gmm<1, 4><<<dim3(392 * 2), blk, 0, stream>>>(
      big16, wbf + O_C2, c2_b, out, NTOK, 96, 1728, 2, bn2_g, bn2_b, bn2_m, bn2_v, 0);
  transpose_k<<<dim3(1568, 6), blk, 0, stream>>>(act, out + CONV_OUT_SZ);
}